// Round 1
// baseline (1021.239 us; speedup 1.0000x reference)
//
#include <hip/hip_runtime.h>

#define T_LEN 2048
#define HID 64
#define EMB 128
#define WD 8                 // steps per window (barrier period)
#define NWIN (T_LEN / WD)    // 256
#define NPH (NWIN + 4)       // +4 windows of pipeline lag (C2)
#define PPAD (HID + 4)       // padded inner dim of p-buffers (bank spread)

typedef _Float16 half2_t __attribute__((ext_vector_type(2)));
typedef _Float16 half4 __attribute__((ext_vector_type(4)));
typedef _Float16 half8 __attribute__((ext_vector_type(8)));
typedef float f32x4 __attribute__((ext_vector_type(4)));
typedef unsigned uint4v __attribute__((ext_vector_type(4)));

#if __has_builtin(__builtin_amdgcn_exp2f)
#define EXP2F(x) __builtin_amdgcn_exp2f(x)
#else
#define EXP2F(x) exp2f(x)
#endif
#if __has_builtin(__builtin_amdgcn_rcpf)
#define RCPF(x) __builtin_amdgcn_rcpf(x)
#else
#define RCPF(x) (1.0f / (x))
#endif

#define LOG2E 1.4426950408889634f

__device__ __forceinline__ float fdot2(unsigned a, unsigned b, float c) {
    return __builtin_amdgcn_fdot2(__builtin_bit_cast(half2_t, a),
                                  __builtin_bit_cast(half2_t, b), c, false);
}

// Full-row 64-MAC dot: 8 weight quads vs 8 gathered-h quads, 4 chains.
__device__ __forceinline__ float dotrow(const uint4v* w, const uint4v* g, float init) {
    float a0 = init, a1 = 0.f, a2 = 0.f, a3 = 0.f;
    #pragma unroll
    for (int q = 0; q < 8; ++q) {
        a0 = fdot2(w[q][0], g[q][0], a0);
        a1 = fdot2(w[q][1], g[q][1], a1);
        a2 = fdot2(w[q][2], g[q][2], a2);
        a3 = fdot2(w[q][3], g[q][3], a3);
    }
    return (a0 + a1) + (a2 + a3);
}

__device__ __forceinline__ uint4v pack8(float4 a, float4 b, float s) {
    half2_t h0{(_Float16)(a.x * s), (_Float16)(a.y * s)};
    half2_t h1{(_Float16)(a.z * s), (_Float16)(a.w * s)};
    half2_t h2{(_Float16)(b.x * s), (_Float16)(b.y * s)};
    half2_t h3{(_Float16)(b.z * s), (_Float16)(b.w * s)};
    uint4v q;
    q[0] = __builtin_bit_cast(unsigned, h0);
    q[1] = __builtin_bit_cast(unsigned, h1);
    q[2] = __builtin_bit_cast(unsigned, h2);
    q[3] = __builtin_bit_cast(unsigned, h3);
    return q;
}

// One 64-float weight row -> 8 packed quads, exp2-space prescaled.
__device__ __forceinline__ void cvt8(const float* __restrict__ Wp, float s, uint4v* dst) {
    const float4* p = reinterpret_cast<const float4*>(Wp);
    #pragma unroll
    for (int k = 0; k < 8; ++k) dst[k] = pack8(p[2 * k], p[2 * k + 1], s);
}

// ROUND 16 = ROUND 15 with the PRODUCER waves moved onto MFMA, time-batched
// per window. R15 counters: VALUBusy 81%, MfmaUtil 0, HBM 0.1% -> pure
// VALU-issue-bound; producers (Wih1*h0, Wih2*h1) were 8192 of 20480
// dot-cycles/phase on the 4-cyc v_dot2 path, yet are window-batchable GEMMs
// ([256x64]x[64x8] per phase per layer). New roles:
//   wv0/1/2 = C0/C1/C2 (unchanged dot2 recurrence)      [S0/S1/S2]
//   wv3 = Wih1 producer (MFMA), wv7 = Wih2 producer     [S3, ~500 cyc/phase]
//   wv4/5/6 = barrier-only idlers                       [S0/S1/S2]
// MFMA fragment layout (16x16x32 f16): A/B lane l holds k=4*(l>>4)+{0..3}
// (+16 upper half); B col = l&15 (window step j, cols 8..15 duplicate);
// D row = (l>>4)*4+reg, col = l&15 -> reg r = 4 consecutive gate rows ->
// one ds_write_b128 per tile into p-buf padded to [4][HID+4].
// Producer A-frags bit_cast into the same w[4][8] storage the C waves use
// (roles exclusive) so VGPRs aren't double-booked across the shared loop.
__global__ __launch_bounds__(512)
__attribute__((amdgpu_waves_per_eu(2, 2)))
void lstm3_fused(
    const float* __restrict__ x,
    const float* __restrict__ Wih0, const float* __restrict__ Whh0,
    const float* __restrict__ bih0, const float* __restrict__ bhh0,
    const float* __restrict__ Wih1, const float* __restrict__ Whh1,
    const float* __restrict__ bih1, const float* __restrict__ bhh1,
    const float* __restrict__ Wih2, const float* __restrict__ Whh2,
    const float* __restrict__ bih2, const float* __restrict__ bhh2,
    const float* __restrict__ fcW,  const float* __restrict__ fcb,
    float* __restrict__ out)
{
    const int b   = blockIdx.x;
    const int tid = threadIdx.x;
    const int wv  = tid >> 6;          // 0..7 (wave-uniform role)
    const int L   = tid & 63;          // owned h-index / row-lane

    __shared__ __align__(16) _Float16 h0ring[16][HID];   // 2 windows of h0
    __shared__ __align__(16) _Float16 h1ring[16][HID];   // 2 windows of h1
    __shared__ __align__(16) _Float16 h2ring[2][HID];    // h2 self-ring only
    __shared__ __align__(16) float p1buf[2][WD][4][PPAD]; // wih1 partials
    __shared__ __align__(16) float p2buf[2][WD][4][PPAD]; // wih2 partials
    __shared__ __align__(16) float xs[T_LEN];

    // Stage x[b,0,:] (512 float4 by 512 threads); zero the rings.
    {
        const float4* xg4 = reinterpret_cast<const float4*>(x + b * T_LEN);
        reinterpret_cast<float4*>(xs)[tid] = xg4[tid];
        reinterpret_cast<unsigned*>(h0ring)[tid] = 0u;   // 512 dwords
        reinterpret_cast<unsigned*>(h1ring)[tid] = 0u;
        if (tid < 64) reinterpret_cast<unsigned*>(h2ring)[tid] = 0u;
    }

    const float sI = -LOG2E, sF = -LOG2E, sG = -2.f * LOG2E, sO = -LOG2E;
    const float scl[4] = {sI, sF, sG, sO};

    uint4v w[4][8];                    // C: 4 whh rows; producers: A-frags
    float bias4[4] = {0.f, 0.f, 0.f, 0.f};
    float wx4[4]   = {0.f, 0.f, 0.f, 0.f};

    if (wv < 3) {                      // C_l: whh_l all 4 gate rows
        const float* Wh = (wv == 0) ? Whh0 : (wv == 1) ? Whh1 : Whh2;
        const float* bi = (wv == 0) ? bih0 : (wv == 1) ? bih1 : bih2;
        const float* bh = (wv == 0) ? bhh0 : (wv == 1) ? bhh1 : bhh2;
        #pragma unroll
        for (int c = 0; c < 4; ++c) {
            cvt8(Wh + (c * 64 + L) * 64, scl[c], w[c]);
            bias4[c] = (bi[c * 64 + L] + bh[c * 64 + L]) * scl[c];
        }
        if (wv == 0) {
            #pragma unroll
            for (int c = 0; c < 4; ++c) wx4[c] = Wih0[c * 64 + L] * scl[c];
        }
    } else if (wv == 3 || wv == 7) {   // producer: full Wih as 16 A-tiles x 2
        const float* Wsrc = (wv == 3) ? Wih1 : Wih2;
        const int g4 = (L >> 4) * 4;
        const int mr = L & 15;
        #pragma unroll
        for (int t = 0; t < 16; ++t) {
            const float s = scl[t >> 2];
            const float* rowp = Wsrc + (t * 16 + mr) * 64;
            #pragma unroll
            for (int kf = 0; kf < 2; ++kf) {
                float4 lo = *reinterpret_cast<const float4*>(rowp + kf * 32 + g4);
                float4 hi = *reinterpret_cast<const float4*>(rowp + kf * 32 + 16 + g4);
                half8 a = {(_Float16)(lo.x * s), (_Float16)(lo.y * s),
                           (_Float16)(lo.z * s), (_Float16)(lo.w * s),
                           (_Float16)(hi.x * s), (_Float16)(hi.y * s),
                           (_Float16)(hi.z * s), (_Float16)(hi.w * s)};
                const int idx = t * 2 + kf;
                w[idx >> 3][idx & 7] = __builtin_bit_cast(uint4v, a);
            }
        }
    }
    // wv 4,5,6: idle (barrier participants only)

    float cst = 0.f;                   // cell state (C waves, lane-local)
    __syncthreads();

    for (int ph = 0; ph < NPH; ++ph) {
        const int par = ph & 1;

        if (wv == 0) {
            if (ph < NWIN) {           // h0 window ph
                _Float16* cur = &h0ring[par * 8][0];
                const _Float16* prv = &h0ring[(par ^ 1) * 8][0];
                const int tb = ph * WD;
                #pragma unroll
                for (int j = 0; j < WD; ++j) {
                    const uint4v* hp = reinterpret_cast<const uint4v*>(
                        (j == 0) ? (prv + 7 * HID) : (cur + (j - 1) * HID));
                    uint4v g[8];
                    #pragma unroll
                    for (int k = 0; k < 8; ++k) g[k] = hp[k];
                    float xv = xs[tb + j];
                    float d0 = dotrow(w[0], g, fmaf(wx4[0], xv, bias4[0]));
                    float d1 = dotrow(w[1], g, fmaf(wx4[1], xv, bias4[1]));
                    float d2 = dotrow(w[2], g, fmaf(wx4[2], xv, bias4[2]));
                    float d3 = dotrow(w[3], g, fmaf(wx4[3], xv, bias4[3]));
                    float ai = RCPF(1.f + EXP2F(d0));
                    float af = RCPF(1.f + EXP2F(d1));
                    float ag = fmaf(2.f, RCPF(1.f + EXP2F(d2)), -1.f);
                    float ao = RCPF(1.f + EXP2F(d3));
                    cst = fmaf(af, cst, ai * ag);
                    float tc = fmaf(2.f, RCPF(1.f + EXP2F(-2.f * LOG2E * cst)), -1.f);
                    cur[j * HID + L] = (_Float16)(ao * tc);
                }
            }
        } else if (wv == 1) {
            if (ph >= 2 && ph < NWIN + 2) {    // h1 window ph-2 (p1[par] ready)
                _Float16* cur = &h1ring[par * 8][0];
                const _Float16* prv = &h1ring[(par ^ 1) * 8][0];
                const float (*pb)[4][PPAD] = p1buf[par];
                #pragma unroll
                for (int j = 0; j < WD; ++j) {
                    const uint4v* hp = reinterpret_cast<const uint4v*>(
                        (j == 0) ? (prv + 7 * HID) : (cur + (j - 1) * HID));
                    uint4v g[8];
                    #pragma unroll
                    for (int k = 0; k < 8; ++k) g[k] = hp[k];
                    float d0 = dotrow(w[0], g, bias4[0] + pb[j][0][L]);
                    float d1 = dotrow(w[1], g, bias4[1] + pb[j][1][L]);
                    float d2 = dotrow(w[2], g, bias4[2] + pb[j][2][L]);
                    float d3 = dotrow(w[3], g, bias4[3] + pb[j][3][L]);
                    float ai = RCPF(1.f + EXP2F(d0));
                    float af = RCPF(1.f + EXP2F(d1));
                    float ag = fmaf(2.f, RCPF(1.f + EXP2F(d2)), -1.f);
                    float ao = RCPF(1.f + EXP2F(d3));
                    cst = fmaf(af, cst, ai * ag);
                    float tc = fmaf(2.f, RCPF(1.f + EXP2F(-2.f * LOG2E * cst)), -1.f);
                    cur[j * HID + L] = (_Float16)(ao * tc);
                }
            }
        } else if (wv == 2) {
            if (ph >= 4) {                     // h2 window ph-4 (p2[par] ready)
                const float (*pb)[4][PPAD] = p2buf[par];
                #pragma unroll
                for (int j = 0; j < WD; ++j) {
                    const uint4v* hp = reinterpret_cast<const uint4v*>(
                        &h2ring[(j & 1) ^ 1][0]);
                    uint4v g[8];
                    #pragma unroll
                    for (int k = 0; k < 8; ++k) g[k] = hp[k];
                    float d0 = dotrow(w[0], g, bias4[0] + pb[j][0][L]);
                    float d1 = dotrow(w[1], g, bias4[1] + pb[j][1][L]);
                    float d2 = dotrow(w[2], g, bias4[2] + pb[j][2][L]);
                    float d3 = dotrow(w[3], g, bias4[3] + pb[j][3][L]);
                    float ai = RCPF(1.f + EXP2F(d0));
                    float af = RCPF(1.f + EXP2F(d1));
                    float ag = fmaf(2.f, RCPF(1.f + EXP2F(d2)), -1.f);
                    float ao = RCPF(1.f + EXP2F(d3));
                    cst = fmaf(af, cst, ai * ag);
                    float tc = fmaf(2.f, RCPF(1.f + EXP2F(-2.f * LOG2E * cst)), -1.f);
                    h2ring[j & 1][L] = (_Float16)(ao * tc);
                }
            }
        } else if (wv == 3 || wv == 7) {
            // MFMA producer: full Wih_l GEMM vs the just-published h window.
            // wv3: p1 for window ph-1 (active ph in [1, NWIN]);
            // wv7: p2 for window ph-3 (active ph in [3, NWIN+2]).
            const bool act = (wv == 3) ? (ph >= 1 && ph < NWIN + 1)
                                       : (ph >= 3 && ph < NWIN + 3);
            if (act) {
                const _Float16 (*ring)[HID] = (wv == 3) ? h0ring : h1ring;
                float (*po)[4][PPAD] = ((wv == 3) ? p1buf : p2buf)[par ^ 1];
                const int jj = L & 7;                  // window step (col)
                const int g4 = (L >> 4) * 4;           // k-group base
                const _Float16* rb = &ring[(par ^ 1) * 8 + jj][0];
                half4 b00 = *reinterpret_cast<const half4*>(rb + g4);
                half4 b01 = *reinterpret_cast<const half4*>(rb + 16 + g4);
                half4 b10 = *reinterpret_cast<const half4*>(rb + 32 + g4);
                half4 b11 = *reinterpret_cast<const half4*>(rb + 48 + g4);
                half8 B0 = __builtin_shufflevector(b00, b01, 0, 1, 2, 3, 4, 5, 6, 7);
                half8 B1 = __builtin_shufflevector(b10, b11, 0, 1, 2, 3, 4, 5, 6, 7);
                f32x4 acc[16];
                #pragma unroll
                for (int t = 0; t < 16; ++t) {
                    const int i0 = t * 2, i1 = t * 2 + 1;
                    f32x4 z = {0.f, 0.f, 0.f, 0.f};
                    acc[t] = __builtin_amdgcn_mfma_f32_16x16x32_f16(
                        __builtin_bit_cast(half8, w[i0 >> 3][i0 & 7]), B0, z, 0, 0, 0);
                    acc[t] = __builtin_amdgcn_mfma_f32_16x16x32_f16(
                        __builtin_bit_cast(half8, w[i1 >> 3][i1 & 7]), B1, acc[t], 0, 0, 0);
                }
                if ((L & 15) < 8) {   // cols 8..15 are duplicates -> drop
                    #pragma unroll
                    for (int t = 0; t < 16; ++t) {
                        // D row = 4*(l>>4)+r of tile t -> gate t>>2,
                        // row-in-gate 16*(t&3) + 4*(l>>4) + r (r = acc elem).
                        *reinterpret_cast<f32x4*>(
                            &po[jj][t >> 2][(t & 3) * 16 + g4]) = acc[t];
                    }
                }
            }
        }
        // wv 4,5,6: nothing — barrier only.

        __syncthreads();   // publish window: h rings + p-buffers
    }

    // Final FC (f32): h2[2047] -> slot 2047&1 = 1.
    if (tid < EMB) {
        float acc = fcb[tid];
        const _Float16* hf = &h2ring[1][0];
        const float4* W4 = reinterpret_cast<const float4*>(fcW + tid * HID);
        #pragma unroll
        for (int k = 0; k < 16; ++k) {
            float4 wv4 = W4[k];
            acc = fmaf(wv4.x, (float)hf[4 * k + 0], acc);
            acc = fmaf(wv4.y, (float)hf[4 * k + 1], acc);
            acc = fmaf(wv4.z, (float)hf[4 * k + 2], acc);
            acc = fmaf(wv4.w, (float)hf[4 * k + 3], acc);
        }
        out[b * EMB + tid] = acc;
    }
}

extern "C" void kernel_launch(void* const* d_in, const int* in_sizes, int n_in,
                              void* d_out, int out_size, void* d_ws, size_t ws_size,
                              hipStream_t stream) {
    const float* x    = (const float*)d_in[0];
    const float* Wih0 = (const float*)d_in[1];
    const float* Whh0 = (const float*)d_in[2];
    const float* bih0 = (const float*)d_in[3];
    const float* bhh0 = (const float*)d_in[4];
    const float* Wih1 = (const float*)d_in[5];
    const float* Whh1 = (const float*)d_in[6];
    const float* bih1 = (const float*)d_in[7];
    const float* bhh1 = (const float*)d_in[8];
    const float* Wih2 = (const float*)d_in[9];
    const float* Whh2 = (const float*)d_in[10];
    const float* bih2 = (const float*)d_in[11];
    const float* bhh2 = (const float*)d_in[12];
    const float* fcW  = (const float*)d_in[13];
    const float* fcb  = (const float*)d_in[14];
    float* out = (float*)d_out;

    lstm3_fused<<<dim3(256), dim3(512), 0, stream>>>(
        x, Wih0, Whh0, bih0, bhh0,
        Wih1, Whh1, bih1, bhh1,
        Wih2, Whh2, bih2, bhh2,
        fcW, fcb, out);
}